// Round 2
// baseline (217.687 us; speedup 1.0000x reference)
//
#include <hip/hip_runtime.h>

typedef __bf16 bf16x8 __attribute__((ext_vector_type(8)));
typedef float f32x4 __attribute__((ext_vector_type(4)));

#define BS 2
#define SEQ 2048
#define DM 1024
#define NH 16
#define DKH 64
#define GM 4096
#define GN 1024
#define GK 1024
#define NEGV (-1e9f)

// ws layout (ushort units). At overlaps Xq (Xq dead after projections).
#define OFF_XQ 0u
#define OFF_XK 4194304u
#define OFF_XV 8388608u
#define OFF_WQ 12582912u
#define OFF_WK 13631488u
#define OFF_WV 14680064u
#define OFF_WO 15728640u
#define OFF_QH 16777216u
#define OFF_KH 20971520u
#define OFF_VH 25165824u
#define OFF_AT 0u

__device__ __forceinline__ unsigned short f2b(float f) {
    unsigned u = __builtin_bit_cast(unsigned, f);
    u += 0x7fffu + ((u >> 16) & 1u);
    return (unsigned short)(u >> 16);
}

__global__ __launch_bounds__(256)
void cvt_kernel(const float* __restrict__ q, const float* __restrict__ k,
                const float* __restrict__ v, const float* __restrict__ wq,
                const float* __restrict__ wk, const float* __restrict__ wv,
                const float* __restrict__ wo, ushort* __restrict__ ws)
{
    const float* src; unsigned n; unsigned dst;
    switch (blockIdx.y) {
        case 0: src = q;  n = 4194304u; dst = OFF_XQ; break;
        case 1: src = k;  n = 4194304u; dst = OFF_XK; break;
        case 2: src = v;  n = 4194304u; dst = OFF_XV; break;
        case 3: src = wq; n = 1048576u; dst = OFF_WQ; break;
        case 4: src = wk; n = 1048576u; dst = OFF_WK; break;
        case 5: src = wv; n = 1048576u; dst = OFF_WV; break;
        default: src = wo; n = 1048576u; dst = OFF_WO; break;
    }
    unsigned i = (blockIdx.x * 256u + threadIdx.x) * 4u;
    if (i >= n) return;
    float4 f = *(const float4*)(src + i);
    ushort4 o;
    o.x = f2b(f.x); o.y = f2b(f.y); o.z = f2b(f.z); o.w = f2b(f.w);
    *(ushort4*)(ws + dst + i) = o;
}

// C = A @ B^T, A:[4096][1024] bf16 row-major, B:[1024][1024] bf16 row-major.
// PROJ: z in {0,1,2} selects (Xq,Wq)->Qh etc, bf16 head-split out, z==0 scaled 1/8.
// !PROJ: fp32 plain [4096][1024] out.
template<bool PROJ>
__global__ __launch_bounds__(256)
void gemm_bt(const ushort* __restrict__ Abase, const ushort* __restrict__ Bbase,
             ushort* __restrict__ obf, float* __restrict__ of)
{
    __shared__ __align__(16) ushort lA[128][72];
    __shared__ __align__(16) ushort lB[128][72];

    const ushort* A = Abase;
    const ushort* Bw = Bbase;
    ushort* dst = obf;
    float scale = 1.0f;
    if (PROJ) {
        unsigned z = blockIdx.z;
        A  += (size_t)z * (GM * GK);
        Bw += (size_t)z * (GN * GK);
        dst += (size_t)z * (GM * GN);
        if (z == 0) scale = 0.125f;   // 1/sqrt(64), exact
    }

    const int tid = threadIdx.x;
    const int lane = tid & 63, wid = tid >> 6;
    const int wr = wid >> 1, wc = wid & 1;
    const int lr = lane & 15, lg = lane >> 4;
    const int m0 = blockIdx.y * 128, n0 = blockIdx.x * 128;
    const int srow = tid >> 3, sseg = tid & 7;

    f32x4 acc[4][4] = {};

    for (int k0 = 0; k0 < GK; k0 += 64) {
        __syncthreads();
#pragma unroll
        for (int p = 0; p < 4; ++p) {
            int r = p * 32 + srow;
            *(uint4*)(&lA[r][sseg * 8]) =
                *(const uint4*)(A + (size_t)(m0 + r) * GK + k0 + sseg * 8);
            *(uint4*)(&lB[r][sseg * 8]) =
                *(const uint4*)(Bw + (size_t)(n0 + r) * GK + k0 + sseg * 8);
        }
        __syncthreads();
#pragma unroll
        for (int kk = 0; kk < 2; ++kk) {
            bf16x8 af[4], bfr[4];
#pragma unroll
            for (int i = 0; i < 4; ++i) {
                af[i]  = *(const bf16x8*)(&lA[wr * 64 + i * 16 + lr][kk * 32 + lg * 8]);
                bfr[i] = *(const bf16x8*)(&lB[wc * 64 + i * 16 + lr][kk * 32 + lg * 8]);
            }
#pragma unroll
            for (int i = 0; i < 4; ++i)
#pragma unroll
                for (int j = 0; j < 4; ++j)
                    acc[i][j] = __builtin_amdgcn_mfma_f32_16x16x32_bf16(af[i], bfr[j], acc[i][j], 0, 0, 0);
        }
    }

#pragma unroll
    for (int i = 0; i < 4; ++i) {
#pragma unroll
        for (int j = 0; j < 4; ++j) {
            int col = n0 + wc * 64 + j * 16 + lr;
#pragma unroll
            for (int r = 0; r < 4; ++r) {
                int row = m0 + wr * 64 + i * 16 + lg * 4 + r;
                float val = acc[i][j][r] * scale;
                if (PROJ) {
                    int b = row >> 11, s = row & 2047;
                    int hh = col >> 6, dk = col & 63;
                    dst[(((size_t)b * NH + hh) * SEQ + s) * DKH + dk] = f2b(val);
                } else {
                    of[(size_t)row * GN + col] = val;
                }
            }
        }
    }
}

// Flash attention: block = (b, h, q-tile of 128). 4 waves x 32 q-rows.
__global__ __launch_bounds__(256)
void attn_kernel(ushort* __restrict__ ws, const int* __restrict__ mask)
{
    const int bid = blockIdx.x;
    const int qt = bid & 15;
    const int h  = (bid >> 4) & 15;
    const int b  = bid >> 8;

    const ushort* Qp = ws + OFF_QH + (size_t)(b * NH + h) * (SEQ * DKH);
    const ushort* Kp = ws + OFF_KH + (size_t)(b * NH + h) * (SEQ * DKH);
    const ushort* Vp = ws + OFF_VH + (size_t)(b * NH + h) * (SEQ * DKH);
    ushort* At = ws + OFF_AT;
    const int* mp = mask + (size_t)b * SEQ;   // int32 per position (JAX x64 off)

    // pool aliases: lK [128][72] (staging phase) / per-wave lP [32][136] (softmax+PV phase)
    __shared__ __align__(16) ushort pool[17408];
    __shared__ __align__(16) ushort lV[64][136];  // V transposed: [dk][key]
    ushort (*lK)[72] = (ushort (*)[72])pool;

    const int tid = threadIdx.x;
    const int lane = tid & 63, wid = tid >> 6;
    const int lr = lane & 15, lg = lane >> 4;
    ushort* lPw = pool + wid * (32 * 136);

    // Q fragments (held in registers for all K-tiles)
    bf16x8 qf[2][2];
    const int qrow0 = qt * 128 + wid * 32;
#pragma unroll
    for (int fr = 0; fr < 2; ++fr)
#pragma unroll
        for (int kk = 0; kk < 2; ++kk)
            qf[fr][kk] = *(const bf16x8*)(Qp + (size_t)(qrow0 + fr * 16 + lr) * DKH + kk * 32 + lg * 8);

    f32x4 acc_o[2][4] = {};
    float mrun[2][4], lrun[2][4];
#pragma unroll
    for (int fr = 0; fr < 2; ++fr)
#pragma unroll
        for (int r = 0; r < 4; ++r) { mrun[fr][r] = -INFINITY; lrun[fr][r] = 0.f; }

    const int srow = tid >> 3, sseg = tid & 7;

    for (int kt = 0; kt < SEQ / 128; ++kt) {
        const int kbase = kt * 128;
        __syncthreads();   // previous iter's lP/lV reads done
        // stage K tile [128][64] -> lK (padded rows)
#pragma unroll
        for (int p = 0; p < 4; ++p) {
            int r = p * 32 + srow;
            *(uint4*)(&lK[r][sseg * 8]) =
                *(const uint4*)(Kp + (size_t)(kbase + r) * DKH + sseg * 8);
        }
        // stage V tile transposed -> lV[dk][key]
#pragma unroll
        for (int p = 0; p < 4; ++p) {
            int blk = p * 256 + tid;
            int key = blk >> 3, seg = blk & 7;
            uint4 vv = *(const uint4*)(Vp + (size_t)(kbase + key) * DKH + seg * 8);
            const ushort* pv = (const ushort*)&vv;
#pragma unroll
            for (int j = 0; j < 8; ++j)
                lV[seg * 8 + j][key] = pv[j];
        }
        __syncthreads();

        // S = Q K^T  (scale already folded into Q)
        f32x4 s[2][8];
#pragma unroll
        for (int fc = 0; fc < 8; ++fc) {
            bf16x8 kf0 = *(const bf16x8*)(&lK[fc * 16 + lr][lg * 8]);
            bf16x8 kf1 = *(const bf16x8*)(&lK[fc * 16 + lr][32 + lg * 8]);
#pragma unroll
            for (int fr = 0; fr < 2; ++fr) {
                f32x4 t = {};
                t = __builtin_amdgcn_mfma_f32_16x16x32_bf16(qf[fr][0], kf0, t, 0, 0, 0);
                t = __builtin_amdgcn_mfma_f32_16x16x32_bf16(qf[fr][1], kf1, t, 0, 0, 0);
                s[fr][fc] = t;
            }
        }
        __syncthreads();   // all lK reads complete before lP overwrites pool

        // mask: key positions with mask==0 -> -1e9
        int mv[8];
#pragma unroll
        for (int fc = 0; fc < 8; ++fc) mv[fc] = mp[kbase + fc * 16 + lr];
#pragma unroll
        for (int fc = 0; fc < 8; ++fc)
#pragma unroll
            for (int fr = 0; fr < 2; ++fr)
#pragma unroll
                for (int r = 0; r < 4; ++r)
                    s[fr][fc][r] = (mv[fc] == 0) ? NEGV : s[fr][fc][r];

        // online softmax (wave-parallel: 16-lane shfl reductions)
#pragma unroll
        for (int fr = 0; fr < 2; ++fr) {
#pragma unroll
            for (int r = 0; r < 4; ++r) {
                float mx = s[fr][0][r];
#pragma unroll
                for (int fc = 1; fc < 8; ++fc) mx = fmaxf(mx, s[fr][fc][r]);
                mx = fmaxf(mx, __shfl_xor(mx, 1));
                mx = fmaxf(mx, __shfl_xor(mx, 2));
                mx = fmaxf(mx, __shfl_xor(mx, 4));
                mx = fmaxf(mx, __shfl_xor(mx, 8));
                float mnew = fmaxf(mrun[fr][r], mx);
                float sc = __expf(mrun[fr][r] - mnew);
                mrun[fr][r] = mnew;
                float psum = 0.f;
                const int prow = fr * 16 + lg * 4 + r;
#pragma unroll
                for (int fc = 0; fc < 8; ++fc) {
                    float p = __expf(s[fr][fc][r] - mnew);
                    psum += p;
                    lPw[prow * 136 + fc * 16 + lr] = f2b(p);
                }
                psum += __shfl_xor(psum, 1);
                psum += __shfl_xor(psum, 2);
                psum += __shfl_xor(psum, 4);
                psum += __shfl_xor(psum, 8);
                lrun[fr][r] = lrun[fr][r] * sc + psum;
#pragma unroll
                for (int fc2 = 0; fc2 < 4; ++fc2) acc_o[fr][fc2][r] *= sc;
            }
        }

        // O += P @ V
#pragma unroll
        for (int ks = 0; ks < 4; ++ks) {
            bf16x8 pf[2];
#pragma unroll
            for (int fr = 0; fr < 2; ++fr)
                pf[fr] = *(const bf16x8*)(&lPw[(fr * 16 + lr) * 136 + ks * 32 + lg * 8]);
#pragma unroll
            for (int fc2 = 0; fc2 < 4; ++fc2) {
                bf16x8 vf = *(const bf16x8*)(&lV[fc2 * 16 + lr][ks * 32 + lg * 8]);
#pragma unroll
                for (int fr = 0; fr < 2; ++fr)
                    acc_o[fr][fc2] = __builtin_amdgcn_mfma_f32_16x16x32_bf16(pf[fr], vf, acc_o[fr][fc2], 0, 0, 0);
            }
        }
    }

    // epilogue: divide by row-sum, write concat layout [b][s][h*64+dk] bf16
#pragma unroll
    for (int fr = 0; fr < 2; ++fr) {
        float rl[4];
#pragma unroll
        for (int r = 0; r < 4; ++r) rl[r] = 1.0f / lrun[fr][r];
#pragma unroll
        for (int fc2 = 0; fc2 < 4; ++fc2)
#pragma unroll
            for (int r = 0; r < 4; ++r) {
                int qrow = qrow0 + fr * 16 + lg * 4 + r;
                At[((size_t)(b * SEQ) + qrow) * DM + h * DKH + fc2 * 16 + lr] =
                    f2b(acc_o[fr][fc2][r] * rl[r]);
            }
    }
}

extern "C" void kernel_launch(void* const* d_in, const int* in_sizes, int n_in,
                              void* d_out, int out_size, void* d_ws, size_t ws_size,
                              hipStream_t stream) {
    const float* kin = (const float*)d_in[0];
    const float* vin = (const float*)d_in[1];
    const float* qin = (const float*)d_in[2];
    const int*   msk = (const int*)d_in[3];
    const float* wq  = (const float*)d_in[4];
    const float* wk  = (const float*)d_in[5];
    const float* wv  = (const float*)d_in[6];
    const float* wo  = (const float*)d_in[7];
    ushort* ws = (ushort*)d_ws;
    float* out = (float*)d_out;

    // fp32 -> bf16 of q,k,v and 4 weights
    cvt_kernel<<<dim3(4096, 7), 256, 0, stream>>>(qin, kin, vin, wq, wk, wv, wo, ws);
    // Q/K/V projections (z = 0,1,2), head-split bf16 out, Q scaled by 1/8
    gemm_bt<true><<<dim3(8, 32, 3), 256, 0, stream>>>(ws + OFF_XQ, ws + OFF_WQ, ws + OFF_QH, nullptr);
    // flash attention -> concat bf16
    attn_kernel<<<512, 256, 0, stream>>>(ws, msk);
    // output projection -> fp32 d_out
    gemm_bt<false><<<dim3(8, 32, 1), 256, 0, stream>>>(ws + OFF_AT, ws + OFF_WO, nullptr, out);
}